// Round 3
// baseline (5330.215 us; speedup 1.0000x reference)
//
#include <hip/hip_runtime.h>
#include <hip/hip_bf16.h>
#include <cstdint>

#define B_ 8
#define T_ 2048
#define C_ 2048
#define A_ 2048
#define H_ 32
#define BT_ (B_*T_)

typedef short short8 __attribute__((ext_vector_type(8)));
typedef float floatx4 __attribute__((ext_vector_type(4)));

__device__ __forceinline__ unsigned short f2bf(float f) {
  union { float f; uint32_t u; } a; a.f = f;
  uint32_t r = a.u + 0x7fffu + ((a.u >> 16) & 1u);   // RNE
  return (unsigned short)(r >> 16);
}
__device__ __forceinline__ float bf2f(unsigned short s) {
  union { uint32_t u; float f; } a; a.u = ((uint32_t)s) << 16;
  return a.f;
}

// ---------------- weight prep: hi/lo bf16 split ----------------
__global__ void conv_hilo(const float* __restrict__ s, unsigned short* __restrict__ hi,
                          unsigned short* __restrict__ lo, int n) {
  int i = blockIdx.x * 256 + threadIdx.x;
  if (i < n) {
    float v = s[i];
    unsigned short h = f2bf(v);
    hi[i] = h;
    lo[i] = f2bf(v - bf2f(h));
  }
}

// src (2048 x NV) f32 -> dst (NP x 2048) bf16, rows >= NV zero-padded
__global__ void transpose_pad(const float* __restrict__ s, unsigned short* __restrict__ d, int NP, int NV) {
  int i = blockIdx.x * 256 + threadIdx.x;  // over NP*2048
  int n = i >> 11, kk = i & 2047;
  if (n < NP) d[i] = (n < NV) ? f2bf(s[kk * NV + n]) : (unsigned short)0;
}

// ---------------- token shift + maa_x mix: xxx = x + (shift(x)-x)*time_maa_x (bf16) ----------------
__global__ void shift_mix(const float* __restrict__ x, const float* __restrict__ tmx,
                          unsigned short* __restrict__ xxx) {
  size_t i4 = (size_t)blockIdx.x * 256 + threadIdx.x;   // over BT*C/4
  size_t i = i4 * 4;
  int c = (int)(i & 2047);
  int t = (int)((i >> 11) & 2047);
  float4 xv = *(const float4*)&x[i];
  float4 pv = make_float4(0.f, 0.f, 0.f, 0.f);
  if (t > 0) pv = *(const float4*)&x[i - 2048];
  float4 tv = *(const float4*)&tmx[c];
  ushort4 m;
  m.x = f2bf(xv.x + (pv.x - xv.x) * tv.x);
  m.y = f2bf(xv.y + (pv.y - xv.y) * tv.y);
  m.z = f2bf(xv.z + (pv.z - xv.z) * tv.z);
  m.w = f2bf(xv.w + (pv.w - xv.w) * tv.w);
  *(ushort4*)&xxx[i] = m;
}

// ---------------- async global->LDS helper ----------------
__device__ __forceinline__ void gll16(const void* g, void* l) {
  __builtin_amdgcn_global_load_lds(
      (const __attribute__((address_space(1))) void*)g,
      (__attribute__((address_space(3))) void*)l, 16, 0, 0);
}

// ---------------- plain bf16 GEMM (small-N lora paths): C = A * B^T ----------------
// EPI: 2 = tanh->f32
template<int EPI>
__global__ __launch_bounds__(256)
void gemm_bt(const unsigned short* __restrict__ Am, const unsigned short* __restrict__ Bm,
             void* __restrict__ Cp, int M, int N, int K) {
  __shared__ unsigned short As[128 * 32];
  __shared__ unsigned short Bs[128 * 32];
  const int tid = threadIdx.x;
  const int wid = tid >> 6, lane = tid & 63;
  const int quad = lane >> 4, l15 = lane & 15;
  const long bm = (long)blockIdx.x * 128, bn = (long)blockIdx.y * 128;
  const int wm = (wid & 1) * 64, wn = (wid >> 1) * 64;

  floatx4 acc[4][4];
#pragma unroll
  for (int a = 0; a < 4; a++)
#pragma unroll
    for (int b = 0; b < 4; b++) { floatx4 z = {0.f, 0.f, 0.f, 0.f}; acc[a][b] = z; }

  const int stg_row = wid * 32 + (lane >> 2);
  const int stg_k   = (lane & 3) * 8;
  const int stg_lds = wid * 1024 + lane * 8;

  for (int k0 = 0; k0 < K; k0 += 32) {
    __syncthreads();
#pragma unroll
    for (int p = 0; p < 2; ++p) {
      gll16(Am + (bm + stg_row + p * 16) * (long)K + k0 + stg_k, &As[stg_lds + p * 512]);
      gll16(Bm + (bn + stg_row + p * 16) * (long)K + k0 + stg_k, &Bs[stg_lds + p * 512]);
    }
    __syncthreads();

    short8 af[4], bfr[4];
#pragma unroll
    for (int mi = 0; mi < 4; mi++) af[mi] = *(const short8*)&As[(wm + mi * 16 + l15) * 32 + quad * 8];
#pragma unroll
    for (int ni = 0; ni < 4; ni++) bfr[ni] = *(const short8*)&Bs[(wn + ni * 16 + l15) * 32 + quad * 8];
#pragma unroll
    for (int mi = 0; mi < 4; mi++)
#pragma unroll
      for (int ni = 0; ni < 4; ni++)
        acc[mi][ni] = __builtin_amdgcn_mfma_f32_16x16x32_bf16(af[mi], bfr[ni], acc[mi][ni], 0, 0, 0);
  }

#pragma unroll
  for (int mi = 0; mi < 4; mi++)
#pragma unroll
    for (int ni = 0; ni < 4; ni++)
#pragma unroll
      for (int vv = 0; vv < 4; ++vv) {
        long row = bm + wm + mi * 16 + quad * 4 + vv;
        long col = bn + wn + ni * 16 + l15;
        float val = acc[mi][ni][vv];
        if (EPI == 2) ((float*)Cp)[row * N + col] = tanhf(val);
      }
}

// ---------------- split-B GEMM: C = A * (Bh+Bl)^T  (weight-exact) ----------------
// EPI: 0 = ->bf16, 1 = silu->bf16, 3 = ->f32
template<int EPI>
__global__ __launch_bounds__(256)
void gemm_sb(const unsigned short* __restrict__ Am, const unsigned short* __restrict__ Bhm,
             const unsigned short* __restrict__ Blm, void* __restrict__ Cp, int M, int N, int K) {
  __shared__ unsigned short As[128 * 32];
  __shared__ unsigned short Bhs[128 * 32];
  __shared__ unsigned short Bls[128 * 32];
  const int tid = threadIdx.x;
  const int wid = tid >> 6, lane = tid & 63;
  const int quad = lane >> 4, l15 = lane & 15;
  const long bm = (long)blockIdx.x * 128, bn = (long)blockIdx.y * 128;
  const int wm = (wid & 1) * 64, wn = (wid >> 1) * 64;

  floatx4 acc[4][4];
#pragma unroll
  for (int a = 0; a < 4; a++)
#pragma unroll
    for (int b = 0; b < 4; b++) { floatx4 z = {0.f, 0.f, 0.f, 0.f}; acc[a][b] = z; }

  const int stg_row = wid * 32 + (lane >> 2);
  const int stg_k   = (lane & 3) * 8;
  const int stg_lds = wid * 1024 + lane * 8;

  for (int k0 = 0; k0 < K; k0 += 32) {
    __syncthreads();
#pragma unroll
    for (int p = 0; p < 2; ++p) {
      const long rowA = (bm + stg_row + p * 16) * (long)K + k0 + stg_k;
      const long rowB = (bn + stg_row + p * 16) * (long)K + k0 + stg_k;
      gll16(Am  + rowA, &As [stg_lds + p * 512]);
      gll16(Bhm + rowB, &Bhs[stg_lds + p * 512]);
      gll16(Blm + rowB, &Bls[stg_lds + p * 512]);
    }
    __syncthreads();

    short8 af[4], bh[4], bl[4];
#pragma unroll
    for (int mi = 0; mi < 4; mi++) af[mi] = *(const short8*)&As[(wm + mi * 16 + l15) * 32 + quad * 8];
#pragma unroll
    for (int ni = 0; ni < 4; ni++) {
      bh[ni] = *(const short8*)&Bhs[(wn + ni * 16 + l15) * 32 + quad * 8];
      bl[ni] = *(const short8*)&Bls[(wn + ni * 16 + l15) * 32 + quad * 8];
    }
#pragma unroll
    for (int mi = 0; mi < 4; mi++)
#pragma unroll
      for (int ni = 0; ni < 4; ni++) {
        acc[mi][ni] = __builtin_amdgcn_mfma_f32_16x16x32_bf16(af[mi], bh[ni], acc[mi][ni], 0, 0, 0);
        acc[mi][ni] = __builtin_amdgcn_mfma_f32_16x16x32_bf16(af[mi], bl[ni], acc[mi][ni], 0, 0, 0);
      }
  }

#pragma unroll
  for (int mi = 0; mi < 4; mi++)
#pragma unroll
    for (int ni = 0; ni < 4; ni++)
#pragma unroll
      for (int vv = 0; vv < 4; ++vv) {
        long row = bm + wm + mi * 16 + quad * 4 + vv;
        long col = bn + wn + ni * 16 + l15;
        float val = acc[mi][ni][vv];
        if (EPI == 0) {
          ((unsigned short*)Cp)[row * N + col] = f2bf(val);
        } else if (EPI == 1) {
          float s = val / (1.f + __expf(-val));
          ((unsigned short*)Cp)[row * N + col] = f2bf(s);
        } else {
          ((float*)Cp)[row * N + col] = val;
        }
      }
}

// ---------------- 3-term GEMM: C = Ah*Bh^T + Ah*Bl^T + Al*Bh^T -> f32 (final proj) ----------------
__global__ __launch_bounds__(256)
void gemm_s3(const unsigned short* __restrict__ Ahm, const unsigned short* __restrict__ Alm,
             const unsigned short* __restrict__ Bhm, const unsigned short* __restrict__ Blm,
             float* __restrict__ Cp, int M, int N, int K) {
  __shared__ unsigned short Ahs[128 * 32];
  __shared__ unsigned short Als[128 * 32];
  __shared__ unsigned short Bhs[128 * 32];
  __shared__ unsigned short Bls[128 * 32];
  const int tid = threadIdx.x;
  const int wid = tid >> 6, lane = tid & 63;
  const int quad = lane >> 4, l15 = lane & 15;
  const long bm = (long)blockIdx.x * 128, bn = (long)blockIdx.y * 128;
  const int wm = (wid & 1) * 64, wn = (wid >> 1) * 64;

  floatx4 acc[4][4];
#pragma unroll
  for (int a = 0; a < 4; a++)
#pragma unroll
    for (int b = 0; b < 4; b++) { floatx4 z = {0.f, 0.f, 0.f, 0.f}; acc[a][b] = z; }

  const int stg_row = wid * 32 + (lane >> 2);
  const int stg_k   = (lane & 3) * 8;
  const int stg_lds = wid * 1024 + lane * 8;

  for (int k0 = 0; k0 < K; k0 += 32) {
    __syncthreads();
#pragma unroll
    for (int p = 0; p < 2; ++p) {
      const long rowA = (bm + stg_row + p * 16) * (long)K + k0 + stg_k;
      const long rowB = (bn + stg_row + p * 16) * (long)K + k0 + stg_k;
      gll16(Ahm + rowA, &Ahs[stg_lds + p * 512]);
      gll16(Alm + rowA, &Als[stg_lds + p * 512]);
      gll16(Bhm + rowB, &Bhs[stg_lds + p * 512]);
      gll16(Blm + rowB, &Bls[stg_lds + p * 512]);
    }
    __syncthreads();

    short8 ah[4], al[4], bh[4], bl[4];
#pragma unroll
    for (int mi = 0; mi < 4; mi++) {
      ah[mi] = *(const short8*)&Ahs[(wm + mi * 16 + l15) * 32 + quad * 8];
      al[mi] = *(const short8*)&Als[(wm + mi * 16 + l15) * 32 + quad * 8];
    }
#pragma unroll
    for (int ni = 0; ni < 4; ni++) {
      bh[ni] = *(const short8*)&Bhs[(wn + ni * 16 + l15) * 32 + quad * 8];
      bl[ni] = *(const short8*)&Bls[(wn + ni * 16 + l15) * 32 + quad * 8];
    }
#pragma unroll
    for (int mi = 0; mi < 4; mi++)
#pragma unroll
      for (int ni = 0; ni < 4; ni++) {
        acc[mi][ni] = __builtin_amdgcn_mfma_f32_16x16x32_bf16(ah[mi], bh[ni], acc[mi][ni], 0, 0, 0);
        acc[mi][ni] = __builtin_amdgcn_mfma_f32_16x16x32_bf16(ah[mi], bl[ni], acc[mi][ni], 0, 0, 0);
        acc[mi][ni] = __builtin_amdgcn_mfma_f32_16x16x32_bf16(al[mi], bh[ni], acc[mi][ni], 0, 0, 0);
      }
  }

#pragma unroll
  for (int mi = 0; mi < 4; mi++)
#pragma unroll
    for (int ni = 0; ni < 4; ni++)
#pragma unroll
      for (int vv = 0; vv < 4; ++vv) {
        long row = bm + wm + mi * 16 + quad * 4 + vv;
        long col = bn + wn + ni * 16 + l15;
        Cp[row * N + col] = acc[mi][ni][vv];
      }
}

// ---------------- fused LoRA-mix (xx recomputed inline) ----------------
__global__ __launch_bounds__(256)
void mix_lora(const float* __restrict__ x,
              const float* __restrict__ m5, const float* __restrict__ w2,
              const float* __restrict__ tmw, const float* __restrict__ tmk,
              const float* __restrict__ tmv, const float* __restrict__ tmr,
              const float* __restrict__ tmg,
              unsigned short* __restrict__ xw, unsigned short* __restrict__ xk,
              unsigned short* __restrict__ xv, unsigned short* __restrict__ xr,
              unsigned short* __restrict__ xg) {
  const int bt0 = blockIdx.x * 16;
  const int tid = threadIdx.x;
  const float* tms[5] = {tmw, tmk, tmv, tmr, tmg};
  unsigned short* outs[5] = {xw, xk, xv, xr, xg};
  for (int cc = 0; cc < 8; ++cc) {
    const int c = cc * 256 + tid;
    float xv_[16], xxv_[16];
#pragma unroll
    for (int b = 0; b < 16; b++) {
      const int bt = bt0 + b;
      size_t idx = ((size_t)bt << 11) + c;
      float xc = x[idx];
      float xp = ((bt & 2047) > 0) ? x[idx - 2048] : 0.f;
      xv_[b] = xc; xxv_[b] = xp - xc;
    }
#pragma unroll
    for (int f = 0; f < 5; ++f) {
      const float tmf = tms[f][c];
      float acc[16];
#pragma unroll
      for (int b = 0; b < 16; b++) acc[b] = 0.f;
      for (int dc = 0; dc < 8; ++dc) {
        float wv0 = w2[((size_t)(f * 32 + dc * 4 + 0) << 11) + c];
        float wv1 = w2[((size_t)(f * 32 + dc * 4 + 1) << 11) + c];
        float wv2 = w2[((size_t)(f * 32 + dc * 4 + 2) << 11) + c];
        float wv3 = w2[((size_t)(f * 32 + dc * 4 + 3) << 11) + c];
#pragma unroll
        for (int b = 0; b < 16; b++) {
          float4 mv = *(const float4*)&m5[((size_t)(bt0 + b) << 8) + f * 32 + dc * 4];
          acc[b] += mv.x * wv0 + mv.y * wv1 + mv.z * wv2 + mv.w * wv3;
        }
      }
#pragma unroll
      for (int b = 0; b < 16; b++) {
        size_t idx = ((size_t)(bt0 + b) << 11) + c;
        outs[f][idx] = f2bf(xv_[b] + xxv_[b] * (tmf + acc[b]));
      }
    }
  }
}

// ---------------- decay: dec = exp(-exp(td + t1 @ decay_w2)) (f32) ----------------
__global__ __launch_bounds__(256)
void decay_kernel(const float* __restrict__ t1, const float* __restrict__ w2d,
                  const float* __restrict__ td, float* __restrict__ dec) {
  const int bt0 = blockIdx.x * 16;
  const int tid = threadIdx.x;
  for (int cc = 0; cc < 8; ++cc) {
    const int a = cc * 256 + tid;
    const float tda = td[a];
    float acc[16];
#pragma unroll
    for (int b = 0; b < 16; b++) acc[b] = 0.f;
    for (int dc = 0; dc < 16; ++dc) {
      float wv0 = w2d[((size_t)(dc * 4 + 0) << 11) + a];
      float wv1 = w2d[((size_t)(dc * 4 + 1) << 11) + a];
      float wv2 = w2d[((size_t)(dc * 4 + 2) << 11) + a];
      float wv3 = w2d[((size_t)(dc * 4 + 3) << 11) + a];
#pragma unroll
      for (int b = 0; b < 16; b++) {
        float4 mv = *(const float4*)&t1[((size_t)(bt0 + b) << 7) + dc * 4];
        acc[b] += mv.x * wv0 + mv.y * wv1 + mv.z * wv2 + mv.w * wv3;
      }
    }
#pragma unroll
    for (int b = 0; b < 16; b++) {
      dec[((size_t)(bt0 + b) << 11) + a] = __expf(-__expf(tda + acc[b]));
    }
  }
}

// ---------------- WKV6 scan + fused GroupNorm*g epilogue ----------------
// block = one (b,h); wave w owns channels [16w,16w+16), lane j = state column.
// Writes z_hi over g (in-place) and z_lo over the r buffer (row t of r is dead after step t;
// block (b,h) owns exactly columns h*64..h*64+63 -> no cross-block hazard).
template<int KF32>
__global__ __launch_bounds__(256)
void wkv6_fused(const unsigned short* __restrict__ r, const unsigned short* __restrict__ k16,
                const float* __restrict__ k32, const float* __restrict__ v,
                const float* __restrict__ dec, const float* __restrict__ u,
                unsigned short* __restrict__ g_zhi, unsigned short* __restrict__ zlo,
                const float* __restrict__ lnw, const float* __restrict__ lnb) {
  const int bh = blockIdx.x;
  const int b = bh >> 5, h = bh & 31;
  const int tid = threadIdx.x;
  const int w = __builtin_amdgcn_readfirstlane(tid >> 6);
  const int j = tid & 63;
  __shared__ float ypart[4][64];
  float S[16];
#pragma unroll
  for (int ii = 0; ii < 16; ii++) S[ii] = 0.f;
  float uu[16];
#pragma unroll
  for (int ii = 0; ii < 16; ii++) uu[ii] = u[h * 64 + w * 16 + ii];
  const float la = lnw[h * 64 + j], lb = lnb[h * 64 + j];
  const size_t base = ((size_t)b * T_) * (size_t)A_ + h * 64;
  for (int t = 0; t < T_; ++t) {
    const size_t o = base + (size_t)t * A_;
    const float vj = v[o + j];
    float rr[16], kk[16], dd[16];
#pragma unroll
    for (int dc = 0; dc < 4; ++dc) {
      ushort4 r4 = *(const ushort4*)&r[o + w * 16 + dc * 4];
      float4  d4 = *(const float4*)&dec[o + w * 16 + dc * 4];
      rr[dc * 4 + 0] = bf2f(r4.x); rr[dc * 4 + 1] = bf2f(r4.y);
      rr[dc * 4 + 2] = bf2f(r4.z); rr[dc * 4 + 3] = bf2f(r4.w);
      if (KF32) {
        float4 k4 = *(const float4*)&k32[o + w * 16 + dc * 4];
        kk[dc * 4 + 0] = k4.x; kk[dc * 4 + 1] = k4.y;
        kk[dc * 4 + 2] = k4.z; kk[dc * 4 + 3] = k4.w;
      } else {
        ushort4 k4 = *(const ushort4*)&k16[o + w * 16 + dc * 4];
        kk[dc * 4 + 0] = bf2f(k4.x); kk[dc * 4 + 1] = bf2f(k4.y);
        kk[dc * 4 + 2] = bf2f(k4.z); kk[dc * 4 + 3] = bf2f(k4.w);
      }
      dd[dc * 4 + 0] = d4.x; dd[dc * 4 + 1] = d4.y;
      dd[dc * 4 + 2] = d4.z; dd[dc * 4 + 3] = d4.w;
    }
    float yacc = 0.f;
#pragma unroll
    for (int ii = 0; ii < 16; ii++) {
      float kv = kk[ii] * vj;
      float t2 = fmaf(uu[ii], kv, S[ii]);
      yacc = fmaf(rr[ii], t2, yacc);
      S[ii] = fmaf(dd[ii], S[ii], kv);
    }
    ypart[w][j] = yacc;
    __syncthreads();                      // all reads of row t complete before overlay writes
    if (w == 0) {
      float yj = ypart[0][j] + ypart[1][j] + ypart[2][j] + ypart[3][j];
      float s = yj, s2 = yj * yj;
#pragma unroll
      for (int d = 32; d > 0; d >>= 1) {
        s  += __shfl_xor(s,  d, 64);
        s2 += __shfl_xor(s2, d, 64);
      }
      float mu = s * (1.f / 64.f);
      float var = s2 * (1.f / 64.f) - mu * mu;
      float rs = rsqrtf(var + 6.4e-4f);   // EPS = 1e-5 * 64
      float yn = (yj - mu) * rs * la + lb;
      float z = yn * bf2f(g_zhi[o + j]);
      unsigned short zh = f2bf(z);
      g_zhi[o + j] = zh;
      zlo[o + j] = f2bf(z - bf2f(zh));
    }
    __syncthreads();
  }
}

// ---------------- launch ----------------
extern "C" void kernel_launch(void* const* d_in, const int* in_sizes, int n_in,
                              void* d_out, int out_size, void* d_ws, size_t ws_size,
                              hipStream_t stream) {
  (void)in_sizes; (void)n_in; (void)out_size;
  const float* x   = (const float*)d_in[0];
  const float* tmx = (const float*)d_in[1];
  const float* tmw = (const float*)d_in[2];
  const float* tmk = (const float*)d_in[3];
  const float* tmv = (const float*)d_in[4];
  const float* tmr = (const float*)d_in[5];
  const float* tmg = (const float*)d_in[6];
  const float* w1  = (const float*)d_in[7];   // (C,160)
  const float* w2  = (const float*)d_in[8];   // (5,32,C)
  const float* td  = (const float*)d_in[9];   // (A)
  const float* dw1 = (const float*)d_in[10];  // (C,64)
  const float* dw2 = (const float*)d_in[11];  // (64,A)
  const float* u   = (const float*)d_in[12];  // (H,N)
  const float* Wr  = (const float*)d_in[13];
  const float* Wk  = (const float*)d_in[14];
  const float* Wv  = (const float*)d_in[15];
  const float* Wg  = (const float*)d_in[16];
  const float* Wo  = (const float*)d_in[17];
  const float* lnw = (const float*)d_in[18];
  const float* lnb = (const float*)d_in[19];

  char* ws = (char*)d_ws;
  const size_t MB = 1024 * 1024;
  // 472MB layout (proven safe footprint), lifetime-overlapped:
  // [0,64)    U0: xxx -> g -> z_hi (in place)
  // [64,80)       m5 (f32, 16MB) -> later v-f32 lower half spans [64,128)
  // [128,192) U2: bxk (w1T scratch at [128,129) pre-mix) -> v-f32 upper half
  // [192,256) U3: bxv -> dec lower half
  // [256,320) U4: bxw -> dec upper half     (dec = [192,320) f32)
  // [320,384) U5: bxg -> r -> z_lo overlay
  // [384,448) U6: bxr -> k (bf16, L0)
  // [448,464)     W_hi/W_lo scratch (dw1T at [448,448.5) pre)
  // [464,472)     t1 (f32, 8MB)
  unsigned short* xxx  = (unsigned short*)(ws + 0 * MB);
  unsigned short* gb   = (unsigned short*)(ws + 0 * MB);     // z_hi
  float*          m5   = (float*)(ws + 64 * MB);
  float*          vf   = (float*)(ws + 64 * MB);             // v f32 [64,192)
  unsigned short* w1T  = (unsigned short*)(ws + 128 * MB);
  unsigned short* bxk  = (unsigned short*)(ws + 128 * MB);
  unsigned short* bxv  = (unsigned short*)(ws + 192 * MB);
  float*          decb = (float*)(ws + 192 * MB);            // dec f32 [192,320)
  unsigned short* bxw  = (unsigned short*)(ws + 256 * MB);
  unsigned short* bxg  = (unsigned short*)(ws + 320 * MB);
  unsigned short* rb   = (unsigned short*)(ws + 320 * MB);   // r, then z_lo overlay
  unsigned short* bxr  = (unsigned short*)(ws + 384 * MB);
  unsigned short* kb   = (unsigned short*)(ws + 384 * MB);   // k bf16 (L0)
  unsigned short* dw1T = (unsigned short*)(ws + 448 * MB);
  unsigned short* Whi  = (unsigned short*)(ws + 448 * MB);
  unsigned short* Wlo  = (unsigned short*)(ws + 456 * MB);
  float*          t1   = (float*)(ws + 464 * MB);
  // optional upgrade: k in f32 at [480,608) if workspace allows (runtime-constant branch)
  const bool kf32 = ws_size >= (size_t)616 * MB;
  float* kf = (float*)(ws + 480 * MB);

  const int nW = A_ * C_;  // 4.19M elements
  const size_t EBT = (size_t)BT_ * C_;

  // 1. token-shift mix -> xxx
  shift_mix<<<(int)(EBT / 4 / 256), 256, 0, stream>>>(x, tmx, xxx);

  // 2. m5 = tanh(xxx @ maa_w1) padded N=256
  transpose_pad<<<(256 * 2048) / 256, 256, 0, stream>>>(w1, w1T, 256, 160);
  gemm_bt<2><<<dim3(BT_ / 128, 2), 256, 0, stream>>>(xxx, w1T, m5, BT_, 256, 2048);

  // 3. five mixed inputs
  mix_lora<<<BT_ / 16, 256, 0, stream>>>(x, m5, w2, tmw, tmk, tmv, tmr, tmg,
                                         bxw, bxk, bxv, bxr, bxg);

  // 4. t1 = tanh(xw @ decay_w1) padded N=128
  transpose_pad<<<(128 * 2048) / 256, 256, 0, stream>>>(dw1, dw1T, 128, 64);
  gemm_bt<2><<<dim3(BT_ / 128, 1), 256, 0, stream>>>(bxw, dw1T, t1, BT_, 128, 2048);

  // 5-8. projections with split-exact weights (order matters for slot recycling)
  conv_hilo<<<nW / 256, 256, 0, stream>>>(Wg, Whi, Wlo, nW);
  gemm_sb<1><<<dim3(BT_ / 128, 16), 256, 0, stream>>>(bxg, Whi, Wlo, gb, BT_, 2048, 2048);
  conv_hilo<<<nW / 256, 256, 0, stream>>>(Wr, Whi, Wlo, nW);
  gemm_sb<0><<<dim3(BT_ / 128, 16), 256, 0, stream>>>(bxr, Whi, Wlo, rb, BT_, 2048, 2048);
  conv_hilo<<<nW / 256, 256, 0, stream>>>(Wk, Whi, Wlo, nW);
  if (kf32) {
    gemm_sb<3><<<dim3(BT_ / 128, 16), 256, 0, stream>>>(bxk, Whi, Wlo, kf, BT_, 2048, 2048);
  } else {
    gemm_sb<0><<<dim3(BT_ / 128, 16), 256, 0, stream>>>(bxk, Whi, Wlo, kb, BT_, 2048, 2048);
  }
  conv_hilo<<<nW / 256, 256, 0, stream>>>(Wv, Whi, Wlo, nW);
  gemm_sb<3><<<dim3(BT_ / 128, 16), 256, 0, stream>>>(bxv, Whi, Wlo, vf, BT_, 2048, 2048);

  // 9. dec (after bxv/bxw are dead; overlays them)
  decay_kernel<<<BT_ / 16, 256, 0, stream>>>(t1, dw2, td, decb);

  // 10. WKV6 scan + fused GroupNorm*g -> z_hi (over g), z_lo (over r)
  if (kf32) {
    wkv6_fused<1><<<256, 256, 0, stream>>>(rb, kb, kf, vf, decb, u, gb, rb, lnw, lnb);
  } else {
    wkv6_fused<0><<<256, 256, 0, stream>>>(rb, kb, kf, vf, decb, u, gb, rb, lnw, lnb);
  }

  // 11. output projection: (z_hi + z_lo) @ (Wo_hi + Wo_lo)^T -> d_out (f32)
  conv_hilo<<<nW / 256, 256, 0, stream>>>(Wo, Whi, Wlo, nW);
  gemm_s3<<<dim3(BT_ / 128, 16), 256, 0, stream>>>(gb, rb, Whi, Wlo, (float*)d_out, BT_, 2048, 2048);
}